// Round 11
// baseline (783.062 us; speedup 1.0000x reference)
//
#include <hip/hip_runtime.h>
#include <math.h>

// Problem dims
#define H_   192
#define W_   192
#define C_   128
#define CS_  24

// branch 0 (m1)
#define DM0  32
#define DI0  64
#define L0   2304
#define LT0  2305
#define NS0  64

// branches 1+2 (m2, shared weights) run as 128 sequences
#define DM2  24
#define DI2  48
#define L12  3072
#define LT12 3073
#define NS12 128

#define DST  16
// per-branch chunk counts (NC is a template param; CL = ceil(LT/NC)).
// Round-9 proved the occupancy lever on front12: LDS 28,672B -> 5 blk/CU ->
// VALUBusy 68->75%, -9% time. Round-10: front0 at 29,696B did NOT get the 5th
// block (total regressed to the predicted failure band) — the LDS reserve
// boundary is between 143.4KB and 148.5KB aggregate. Round-11 puts front0 at
// EXACTLY the proven 28,672B: NC0=112 -> CL=21, NR=24 -> 7,168 floats.
// CL=21 makes the tail chunk nt even (c=109: nt=16); phase 2a's pair count is
// changed to (nt+4)/2 — bit-identical for odd nt, covers the extra row for
// even nt (row nt+2 holds the real last token).
#define NC0   112
#define CL0   ((LT0 + NC0 - 1) / NC0)     // 21  (NR=24) -> front0 LDS 28,672B (proven value)
#define NC12  80
#define CL12  ((LT12 + NC12 - 1) / NC12)  // 39  (NR=42) -> front12 LDS 28,672B (5 blk/CU proven)

__device__ __forceinline__ float sigmoidf_(float x){ return 1.f/(1.f+__expf(-x)); }
__device__ __forceinline__ float siluf_(float x){ return x*sigmoidf_(x); }
__device__ __forceinline__ float softplusf_(float x){ return (x > 20.f) ? x : log1pf(__expf(x)); }
__device__ __forceinline__ float exp2_(float x){
#if __has_builtin(__builtin_amdgcn_exp2f)
  return __builtin_amdgcn_exp2f(x);
#else
  return exp2f(x);
#endif
}
#define LOG2E_ 1.44269504088896f

#define LD4(p)  (*(const float4*)(p))
#define ST4(p,v) (*(float4*)(p) = (v))

// ======== front: gather+LN+in_proj+conv+silu+x_proj+dt+scan1-compose ========
// Round-6 phase structure, byte-exact except phase-2a's parity-safe bound.
// Round-7 lesson: LDS=32768 gives NO 5th block (exact 160KiB fit, no slack
// for runtime reserve); 28,672 works (round 9). Round-8 lesson: phase-1
// gather staging is pure overhead (latency already hidden) — do not stage.
// Round-2: no launch_bounds min-occupancy arg (spills); `#pragma unroll 2`.
template<int DM, int DI, int LT, int CL, int NC, int BID>
__global__ __launch_bounds__(256) void front(
    const float* __restrict__ x, const float* __restrict__ gt,
    const float* __restrict__ nw, const float* __restrict__ nb,
    const float* __restrict__ win, const float* __restrict__ cw,
    const float* __restrict__ cb, const float* __restrict__ xpw,
    const float* __restrict__ dtw, const float* __restrict__ dtb,
    const float* __restrict__ Alog,
    float* __restrict__ XS, float* __restrict__ DT,
    float* __restrict__ Bb, float* __restrict__ Cb, float* __restrict__ GATE,
    float* __restrict__ PRD, float* __restrict__ ACC, int seq0)
{
  constexpr int NR  = CL + 3;                  // 24 / 42
  constexpr int R3A = DM*2*DI;                 // wint [k][col]
  constexpr int R3B = CL*36 + DI*36;           // dbl [CL][36] + xpwt [DI][36] (padded)
  constexpr int R3  = (R3A > R3B) ? R3A : R3B;
  __shared__ __align__(16) float smem[2*NR*DI + R3];
  float* xsin = smem;                          // [NR][DI]; phase5+: dtl overlay
  float* dtl  = smem;
  float* xsc  = smem + NR*DI;                  // [NR][DI]; phase1-2: xn [NR][DM]
  float* xn   = xsc;
  float* r3   = smem + 2*NR*DI;
  float* wint = r3;                            // [DM][2*DI] (k-major)
  float* dbl  = r3;                            // [CL][36]: B 0..15, C 16..31, dt 32,33
  float* xpwt = r3 + CL*36;                    // [DI][36]  (k-major, cols 34,35 pad=0)

  const int tid = threadIdx.x;
  const int sc = blockIdx.x / NC, c = blockIdx.x % NC;
  const int gid = seq0 + sc;
  const int t0 = c*CL;
  int nt = LT - t0; if (nt > CL) nt = CL;      // may be <= 0 for tail chunks

  // stage wint[k][col] = win[col*DM + k]
  for (int i = tid; i < DM*2*DI; i += 256) {
    int k = i / (2*DI), col = i - k*(2*DI);
    wint[i] = win[col*DM + k];
  }
  // phase 1: gather + LN -> xn (all NR rows; zero outside sequence)
  {
    int hw = tid >> 5, dm = tid & 31;
    for (int r = hw; r < NR; r += 8) {
      int t = t0 - 3 + r;
      bool inr = (t >= 0 && t < LT);
      float v = 0.f;
      if (inr && dm < DM) {
        if (t == 0) v = gt[dm];
        else {
          int s = t - 1;
          if (BID == 0) {
            int p = s / 48, q = s - p*48;
            int cc = dm*4 + (p&1)*2 + (q&1);
            int ii = p >> 1, jj = q >> 1;
            v = x[cc*(H_*W_) + ((gid>>3)*CS_ + ii)*W_ + (gid&7)*CS_ + jj];
          } else {
            int cc = s / 24, rr = s - cc*24;
            int n = gid & 63, br = gid >> 6;
            int ii = br ? rr : dm;
            int jj = br ? dm : rr;
            v = x[cc*(H_*W_) + ((n>>3)*CS_ + ii)*W_ + (n&7)*CS_ + jj];
          }
        }
      }
      float s1 = (dm < DM) ? v : 0.f;
      float s2 = s1*s1;
      #pragma unroll
      for (int off = 1; off < 32; off <<= 1) {
        s1 += __shfl_xor(s1, off);
        s2 += __shfl_xor(s2, off);
      }
      if (dm < DM) {
        float mean = s1 * (1.f/DM);
        float var = s2 * (1.f/DM) - mean*mean;
        float xv = (v - mean)*rsqrtf(var + 1e-5f)*nw[dm] + nb[dm];
        xn[r*DM + dm] = inr ? xv : 0.f;
      }
    }
  }
  __syncthreads();
  // phase 2a: in_proj xs -> xsin   (2-row x 4-col register tiles)
  // (nt+4)/2 pairs: == (nt+3)/2 for odd nt (bit-identical to round 9); for
  // even tail nt covers rows 0..nt+3 (row nt+2 is the real last token).
  for (int idx = tid; idx < ((nt+4)/2)*(DI/4); idx += 256) {
    int rp = idx / (DI/4), dq = idx - rp*(DI/4);
    int r0 = rp*2, r1 = r0 + 1;
    float ax0=0.f, ay0=0.f, az0=0.f, aw0=0.f;
    float ax1=0.f, ay1=0.f, az1=0.f, aw1=0.f;
    #pragma unroll 2
    for (int kq = 0; kq < DM/4; kq++) {
      float4 xa = LD4(xn + r0*DM + kq*4);
      float4 xb = LD4(xn + r1*DM + kq*4);
      const float* wb = wint + (kq*4)*(2*DI) + dq*4;
      float4 w0 = LD4(wb);
      float4 w1 = LD4(wb + 2*DI);
      float4 w2 = LD4(wb + 4*DI);
      float4 w3 = LD4(wb + 6*DI);
      ax0 += xa.x*w0.x + xa.y*w1.x + xa.z*w2.x + xa.w*w3.x;
      ay0 += xa.x*w0.y + xa.y*w1.y + xa.z*w2.y + xa.w*w3.y;
      az0 += xa.x*w0.z + xa.y*w1.z + xa.z*w2.z + xa.w*w3.z;
      aw0 += xa.x*w0.w + xa.y*w1.w + xa.z*w2.w + xa.w*w3.w;
      ax1 += xb.x*w0.x + xb.y*w1.x + xb.z*w2.x + xb.w*w3.x;
      ay1 += xb.x*w0.y + xb.y*w1.y + xb.z*w2.y + xb.w*w3.y;
      az1 += xb.x*w0.z + xb.y*w1.z + xb.z*w2.z + xb.w*w3.z;
      aw1 += xb.x*w0.w + xb.y*w1.w + xb.z*w2.w + xb.w*w3.w;
    }
    ST4(xsin + r0*DI + dq*4, make_float4(ax0,ay0,az0,aw0));
    ST4(xsin + r1*DI + dq*4, make_float4(ax1,ay1,az1,aw1));
  }
  // phase 2b: in_proj z -> GATE = silu(z)   (2-token x 4-col tiles, tail guard)
  for (int idx = tid; idx < ((nt+1)/2)*(DI/4); idx += 256) {
    int tp = idx / (DI/4), dq = idx - tp*(DI/4);
    int lt0 = tp*2, lt1 = lt0 + 1;
    int r0 = lt0 + 3, r1 = lt1 + 3;       // rows exist (<= NR-1), zero-filled
    float ax0=0.f, ay0=0.f, az0=0.f, aw0=0.f;
    float ax1=0.f, ay1=0.f, az1=0.f, aw1=0.f;
    #pragma unroll 2
    for (int kq = 0; kq < DM/4; kq++) {
      float4 xa = LD4(xn + r0*DM + kq*4);
      float4 xb = LD4(xn + r1*DM + kq*4);
      const float* wb = wint + (kq*4)*(2*DI) + DI + dq*4;
      float4 w0 = LD4(wb);
      float4 w1 = LD4(wb + 2*DI);
      float4 w2 = LD4(wb + 4*DI);
      float4 w3 = LD4(wb + 6*DI);
      ax0 += xa.x*w0.x + xa.y*w1.x + xa.z*w2.x + xa.w*w3.x;
      ay0 += xa.x*w0.y + xa.y*w1.y + xa.z*w2.y + xa.w*w3.y;
      az0 += xa.x*w0.z + xa.y*w1.z + xa.z*w2.z + xa.w*w3.z;
      aw0 += xa.x*w0.w + xa.y*w1.w + xa.z*w2.w + xa.w*w3.w;
      ax1 += xb.x*w0.x + xb.y*w1.x + xb.z*w2.x + xb.w*w3.x;
      ay1 += xb.x*w0.y + xb.y*w1.y + xb.z*w2.y + xb.w*w3.y;
      az1 += xb.x*w0.z + xb.y*w1.z + xb.z*w2.z + xb.w*w3.z;
      aw1 += xb.x*w0.w + xb.y*w1.w + xb.z*w2.w + xb.w*w3.w;
    }
    size_t gb = (size_t)sc*LT + t0;
    ST4(GATE + (gb + lt0)*DI + dq*4,
        make_float4(siluf_(ax0), siluf_(ay0), siluf_(az0), siluf_(aw0)));
    if (lt1 < nt)
      ST4(GATE + (gb + lt1)*DI + dq*4,
          make_float4(siluf_(ax1), siluf_(ay1), siluf_(az1), siluf_(aw1)));
  }
  __syncthreads();
  // phase 3: conv+silu -> xsc (+XS), zero-fill rows >= nt; stage xpwt (padded 36)
  for (int idx = tid; idx < NR*(DI/4); idx += 256) {
    int lt = idx / (DI/4), dq = idx - lt*(DI/4);
    int d0 = dq*4;
    float4 o = make_float4(0.f,0.f,0.f,0.f);
    if (lt < nt) {
      float4 a0 = LD4(xsin + (lt+0)*DI + d0);
      float4 a1 = LD4(xsin + (lt+1)*DI + d0);
      float4 a2 = LD4(xsin + (lt+2)*DI + d0);
      float4 a3 = LD4(xsin + (lt+3)*DI + d0);
      float4 w0 = LD4(cw + (d0+0)*4);
      float4 w1 = LD4(cw + (d0+1)*4);
      float4 w2 = LD4(cw + (d0+2)*4);
      float4 w3 = LD4(cw + (d0+3)*4);
      float4 cbq = LD4(cb + d0);
      o.x = siluf_(cbq.x + w0.x*a0.x + w0.y*a1.x + w0.z*a2.x + w0.w*a3.x);
      o.y = siluf_(cbq.y + w1.x*a0.y + w1.y*a1.y + w1.z*a2.y + w1.w*a3.y);
      o.z = siluf_(cbq.z + w2.x*a0.z + w2.y*a1.z + w2.z*a2.z + w2.w*a3.z);
      o.w = siluf_(cbq.w + w3.x*a0.w + w3.y*a1.w + w3.z*a2.w + w3.w*a3.w);
      ST4(XS + ((size_t)sc*LT + t0 + lt)*DI + d0, o);
    }
    ST4(xsc + lt*DI + d0, o);
  }
  for (int i = tid; i < DI*36; i += 256) {
    int k = i / 36, o = i - k*36;
    xpwt[i] = (o < 34) ? xpw[o*DI + k] : 0.f;
  }
  __syncthreads();
  // phase 4: x_proj (2-token x 4-out tiles) -> dbl (B 0..15, C 16..31, dt 32,33)
  for (int idx = tid; idx < ((nt+1)/2)*9; idx += 256) {
    int tp = idx / 9, oq = idx - tp*9;
    int lt0 = tp*2, lt1 = lt0 + 1;       // lt1 <= nt < NR: row exists (zeros)
    float ax0=0.f, ay0=0.f, az0=0.f, aw0=0.f;
    float ax1=0.f, ay1=0.f, az1=0.f, aw1=0.f;
    #pragma unroll 2
    for (int dq = 0; dq < DI/4; dq++) {
      float4 xa = LD4(xsc + lt0*DI + dq*4);
      float4 xb = LD4(xsc + lt1*DI + dq*4);
      const float* wb = xpwt + (dq*4)*36 + oq*4;
      float4 w0 = LD4(wb);
      float4 w1 = LD4(wb + 36);
      float4 w2 = LD4(wb + 72);
      float4 w3 = LD4(wb + 108);
      ax0 += xa.x*w0.x + xa.y*w1.x + xa.z*w2.x + xa.w*w3.x;
      ay0 += xa.x*w0.y + xa.y*w1.y + xa.z*w2.y + xa.w*w3.y;
      az0 += xa.x*w0.z + xa.y*w1.z + xa.z*w2.z + xa.w*w3.z;
      aw0 += xa.x*w0.w + xa.y*w1.w + xa.z*w2.w + xa.w*w3.w;
      ax1 += xb.x*w0.x + xb.y*w1.x + xb.z*w2.x + xb.w*w3.x;
      ay1 += xb.x*w0.y + xb.y*w1.y + xb.z*w2.y + xb.w*w3.y;
      az1 += xb.x*w0.z + xb.y*w1.z + xb.z*w2.z + xb.w*w3.z;
      aw1 += xb.x*w0.w + xb.y*w1.w + xb.z*w2.w + xb.w*w3.w;
    }
    float av0[4] = {ax0, ay0, az0, aw0};
    float av1[4] = {ax1, ay1, az1, aw1};
    int o0 = oq*4;
    #pragma unroll
    for (int j = 0; j < 4; j++) {
      int o = o0 + j;
      if (o < 2)       dbl[lt0*36 + 32 + o] = av0[j];
      else if (o < 34) dbl[lt0*36 + (o-2)] = av0[j];
    }
    if (lt1 < nt) {
      #pragma unroll
      for (int j = 0; j < 4; j++) {
        int o = o0 + j;
        if (o < 2)       dbl[lt1*36 + 32 + o] = av1[j];
        else if (o < 34) dbl[lt1*36 + (o-2)] = av1[j];
      }
    }
  }
  __syncthreads();
  // phase 4b: vectorized B/C global writes from dbl
  for (int idx = tid; idx < nt*8; idx += 256) {
    int lt = idx >> 3, q = idx & 7;
    float4 v = LD4(dbl + lt*36 + q*4);
    size_t tb = (size_t)sc*LT + t0 + lt;
    if (q < 4) ST4(Bb + tb*DST + q*4, v);
    else       ST4(Cb + tb*DST + (q-4)*4, v);
  }
  // phase 5: dt -> dtl (overlays xsin) + DT
  for (int idx = tid; idx < nt*(DI/4); idx += 256) {
    int lt = idx / (DI/4), dq = idx - lt*(DI/4);
    int d0 = dq*4;
    float t0v = dbl[lt*36 + 32], t1v = dbl[lt*36 + 33];
    float4 w0 = LD4(dtw + 2*d0);
    float4 w1 = LD4(dtw + 2*d0 + 4);
    float4 b4 = LD4(dtb + d0);
    float4 r;
    r.x = softplusf_(t0v*w0.x + t1v*w0.y + b4.x);
    r.y = softplusf_(t0v*w0.z + t1v*w0.w + b4.y);
    r.z = softplusf_(t0v*w1.x + t1v*w1.y + b4.z);
    r.w = softplusf_(t0v*w1.z + t1v*w1.w + b4.w);
    ST4(dtl + lt*DI + d0, r);
    ST4(DT + ((size_t)sc*LT + t0 + lt)*DI + d0, r);
  }
  __syncthreads();
  // phase 6: chunk composition, thread = (d, state-quad); empty chunks emit P=1,S=0
  for (int p = tid; p < DI*4; p += 256) {
    int d = p >> 2, iq = p & 3;
    float4 al = LD4(Alog + d*DST + iq*4);
    float A0 = -__expf(al.x)*LOG2E_, A1 = -__expf(al.y)*LOG2E_;
    float A2 = -__expf(al.z)*LOG2E_, A3 = -__expf(al.w)*LOG2E_;
    float P0=1.f,P1=1.f,P2=1.f,P3=1.f, S0=0.f,S1=0.f,S2=0.f,S3=0.f;
    for (int lt = 0; lt < nt; lt++) {
      float dtv = dtl[lt*DI + d];
      float du = dtv * xsc[lt*DI + d];
      float4 Bq = LD4(dbl + lt*36 + iq*4);
      float a0 = exp2_(dtv*A0), a1 = exp2_(dtv*A1);
      float a2 = exp2_(dtv*A2), a3 = exp2_(dtv*A3);
      P0 *= a0; S0 = S0*a0 + du*Bq.x;
      P1 *= a1; S1 = S1*a1 + du*Bq.y;
      P2 *= a2; S2 = S2*a2 + du*Bq.z;
      P3 *= a3; S3 = S3*a3 + du*Bq.w;
    }
    size_t ob = (size_t)(sc*NC + c)*DI*DST + d*DST + iq*4;
    ST4(PRD + ob, make_float4(P0,P1,P2,P3));
    ST4(ACC + ob, make_float4(S0,S1,S2,S3));
  }
}

// ======== scan2: chunk-level scan; leaves per-chunk h_init in ACC ========
template<int DI, int NC>
__global__ __launch_bounds__(256) void scan2(const float* __restrict__ PRD, float* __restrict__ ACC, int nthread) {
  int tid = blockIdx.x*256 + threadIdx.x;
  if (tid >= nthread) return;
  int sc = tid / (DI*DST);
  int rem = tid - sc*(DI*DST);
  float h = 0.f;
  size_t idx = (size_t)sc*NC*DI*DST + rem;
  #pragma unroll 4
  for (int c = 0; c < NC; c++) {
    float p = PRD[idx];
    float s = ACC[idx];
    ACC[idx] = h;
    h = p*h + s;
    idx += (size_t)DI*DST;
  }
}

// ======== scan3p v2: 4 chunks per 256-thread block, one wave per chunk ========
template<int DM, int DI, int LT, int CL, int NC, int LSEQ>
__global__ __launch_bounds__(256) void scan3p(
    const float* __restrict__ XS, const float* __restrict__ DT,
    const float* __restrict__ Bb, const float* __restrict__ Cb,
    const float* __restrict__ GATE, const float* __restrict__ Alog,
    const float* __restrict__ Dp, const float* __restrict__ ACC,
    const float* __restrict__ wo, float* __restrict__ Y, int seq0)
{
  constexpr int DIP = DI + 4;   // pad to break stride-DI bank pattern
  __shared__ __align__(16) float wot[DM*DIP];
  __shared__ __align__(16) float gl[4][8*DI];
  const int tid = threadIdx.x;
  for (int i = tid; i < DM*DI; i += 256) {
    int dm = i / DI, k = i - dm*DI;
    wot[dm*DIP + k] = wo[i];
  }
  const int lane = tid & 63;
  const int w = tid >> 6;
  const int g = __builtin_amdgcn_readfirstlane(blockIdx.x*4 + w);
  const int sc = g / NC, c = g - (g/NC)*NC;
  float* glw = &gl[w][0];
  int d = lane;
  float A[DST], h[DST];
  float Dd = 0.f;
  if (d < DI) {
    const float4* Ap = (const float4*)(Alog + d*DST);
    #pragma unroll
    for (int q = 0; q < 4; q++) {
      float4 av = Ap[q];
      A[q*4+0] = -__expf(av.x)*LOG2E_; A[q*4+1] = -__expf(av.y)*LOG2E_;
      A[q*4+2] = -__expf(av.z)*LOG2E_; A[q*4+3] = -__expf(av.w)*LOG2E_;
    }
    const float4* hp = (const float4*)(ACC + ((size_t)g*DI + d)*DST);
    #pragma unroll
    for (int q = 0; q < 4; q++) ((float4*)h)[q] = hp[q];
    Dd = Dp[d];
  }
  int t0 = c*CL, t1 = t0 + CL; if (t1 > LT) t1 = LT;
  size_t base = (size_t)sc*LT;
  size_t ybase = (size_t)(seq0 + sc)*LSEQ;
  int bt = 0, tstart = t0;
  __syncthreads();            // wot ready (only block-wide barrier)
  for (int t = t0; t < t1; t++) {
    if (d < DI) {
      size_t tb = base + t;
      float dtv = DT[tb*DI + d];
      float xsv = XS[tb*DI + d];
      float gv  = GATE[tb*DI + d];
      float du = dtv*xsv;
      float Bv[DST], Cv[DST];
      const float4* Bp = (const float4*)(Bb + tb*DST);
      const float4* Cp = (const float4*)(Cb + tb*DST);
      ((float4*)Bv)[0]=Bp[0]; ((float4*)Bv)[1]=Bp[1]; ((float4*)Bv)[2]=Bp[2]; ((float4*)Bv)[3]=Bp[3];
      ((float4*)Cv)[0]=Cp[0]; ((float4*)Cv)[1]=Cp[1]; ((float4*)Cv)[2]=Cp[2]; ((float4*)Cv)[3]=Cp[3];
      float y = 0.f;
      #pragma unroll
      for (int i = 0; i < DST; i++) {
        float a = exp2_(dtv*A[i]);
        h[i] = h[i]*a + du*Bv[i];
        y += h[i]*Cv[i];
      }
      glw[bt*DI + d] = (y + xsv*Dd) * gv;
    }
    bt++;
    if (bt == 8 || t == t1 - 1) {
      // wave-local fence: gl writes retired before cross-lane reads
      asm volatile("s_waitcnt lgkmcnt(0)" ::: "memory");
      __builtin_amdgcn_wave_barrier();
      for (int o = lane; o < bt*DM; o += 64) {
        int b = o / DM, dm = o - b*DM;
        int tt = tstart + b;
        if (tt > 0) {
          float acc = 0.f;
          const float* gr = glw + b*DI;
          const float* wr = wot + dm*DIP;
          #pragma unroll
          for (int kq = 0; kq < DI/4; kq++) {
            float4 g4 = LD4(gr + kq*4);
            float4 w4 = LD4(wr + kq*4);
            acc += g4.x*w4.x + g4.y*w4.y + g4.z*w4.z + g4.w*w4.w;
          }
          Y[(ybase + tt - 1)*DM + dm] = acc;
        }
      }
      // reads retired before next batch overwrites gl
      asm volatile("s_waitcnt lgkmcnt(0)" ::: "memory");
      __builtin_amdgcn_wave_barrier();
      bt = 0; tstart = t + 1;
    }
  }
}

// ======== repack_y0: Y0[n][token(p,q)][dm] -> Y0R[n][c][i][j] ========
__global__ __launch_bounds__(128) void repack_y0(const float* __restrict__ Y0,
                                                 float* __restrict__ Y0R) {
  __shared__ float l[48*33];
  int n = blockIdx.x / 48, p = blockIdx.x - (blockIdx.x/48)*48;
  int tid = threadIdx.x;
  const float* src = Y0 + ((size_t)n*L0 + p*48)*DM0;
  for (int i = tid; i < 48*32; i += 128) {
    int q = i >> 5, dm = i & 31;
    l[q*33 + dm] = src[i];
  }
  __syncthreads();
  int p2 = p >> 1, ppar = p & 1;
  for (int o = tid; o < 1536; o += 128) {
    int dm = o / 48, rem = o - dm*48;
    int qpar = rem / 24, j = rem - qpar*24;
    int c = 4*dm + 2*ppar + qpar;
    Y0R[((size_t)(n*128 + c)*24 + p2)*24 + j] = l[(2*j + qpar)*33 + dm];
  }
}

// ======== fold_out2: all three gathers 576-float contiguous blocks ========
__global__ __launch_bounds__(192) void fold_out2(const float* __restrict__ Y0R,
                                                 const float* __restrict__ Y12,
                                                 float* __restrict__ out) {
  __shared__ float m0l[576];
  __shared__ float o1l[24*25];
  __shared__ float o2l[576];
  int n = blockIdx.x >> 7, c = blockIdx.x & 127;
  int tid = threadIdx.x;
  const float* m0p = Y0R + (size_t)(n*128 + c)*576;
  const float* o1p = Y12 + ((size_t)n*L12 + c*24)*DM2;        // [j][i]
  const float* o2p = Y12 + ((size_t)(64+n)*L12 + c*24)*DM2;   // [i][j]
  for (int i = tid; i < 576; i += 192) {
    m0l[i] = m0p[i];
    int r = i / 24, col = i - r*24;
    o1l[r*25 + col] = o1p[i];
    o2l[i] = o2p[i];
  }
  __syncthreads();
  for (int e = tid; e < 576; e += 192) {
    int hh = e / 192, w = e - hh*192;
    int i = hh*8 + w/24, j = w - (w/24)*24;
    float v = (m0l[i*24 + j] + o1l[j*25 + i] + o2l[i*24 + j]) * (1.f/3.f);
    out[(size_t)c*(H_*W_) + (size_t)(n*3 + hh)*W_ + w] = v;
  }
}

extern "C" void kernel_launch(void* const* d_in, const int* in_sizes, int n_in,
                              void* d_out, int out_size, void* d_ws, size_t ws_size,
                              hipStream_t stream) {
  const float* x       = (const float*)d_in[0];
  const float* norm_w  = (const float*)d_in[1];
  const float* norm_b  = (const float*)d_in[2];
  const float* norm2_w = (const float*)d_in[3];
  const float* norm2_b = (const float*)d_in[4];
  const float* gt1     = (const float*)d_in[5];
  const float* gt2     = (const float*)d_in[6];
  const float* m1_inw  = (const float*)d_in[7];
  const float* m1_cw   = (const float*)d_in[8];
  const float* m1_cb   = (const float*)d_in[9];
  const float* m1_xpw  = (const float*)d_in[10];
  const float* m1_dtw  = (const float*)d_in[11];
  const float* m1_dtb  = (const float*)d_in[12];
  const float* m1_alog = (const float*)d_in[13];
  const float* m1_D    = (const float*)d_in[14];
  const float* m1_ow   = (const float*)d_in[15];
  const float* m2_inw  = (const float*)d_in[16];
  const float* m2_cw   = (const float*)d_in[17];
  const float* m2_cb   = (const float*)d_in[18];
  const float* m2_xpw  = (const float*)d_in[19];
  const float* m2_dtw  = (const float*)d_in[20];
  const float* m2_dtb  = (const float*)d_in[21];
  const float* m2_alog = (const float*)d_in[22];
  const float* m2_D    = (const float*)d_in[23];
  const float* m2_ow   = (const float*)d_in[24];
  float* out = (float*)d_out;

  size_t wsf = ws_size / sizeof(float);

  // persistent projection buffers
  const size_t nY0  = (size_t)NS0*L0*DM0;    // 4,718,592
  const size_t nY12 = (size_t)NS12*L12*DM2;  // 9,437,184
  float* Y0  = (float*)d_ws;
  float* Y12 = Y0 + nY0;
  float* SCR = Y12 + nY12;
  size_t scrf = wsf - (nY0 + nY12);

  // ---- branch 0 (m1), NC=112 (LDS 28,672B — the proven 5 blk/CU value) ----
  {
    const size_t perState = (size_t)NC0*DI0*DST;
    const size_t per = (size_t)LT0*(3*DI0 + 2*DST) + 2*perState;
    int cap = (int)(scrf / per); if (cap < 1) cap = 1; if (cap > NS0) cap = NS0;
    float* XS  = SCR;
    float* DT  = XS + (size_t)cap*LT0*DI0;
    float* Bb  = DT + (size_t)cap*LT0*DI0;
    float* Cb  = Bb + (size_t)cap*LT0*DST;
    float* GT  = Cb + (size_t)cap*LT0*DST;
    float* PRD = GT + (size_t)cap*LT0*DI0;
    float* ACC = PRD + (size_t)cap*perState;
    for (int s0 = 0; s0 < NS0; s0 += cap) {
      int cs = (NS0 - s0 < cap) ? (NS0 - s0) : cap;
      front<DM0, DI0, LT0, CL0, NC0, 0><<<cs*NC0, 256, 0, stream>>>(
          x, gt1, norm_w, norm_b, m1_inw, m1_cw, m1_cb, m1_xpw, m1_dtw, m1_dtb,
          m1_alog, XS, DT, Bb, Cb, GT, PRD, ACC, s0);
      scan2<DI0, NC0><<<(cs*DI0*DST + 255)/256, 256, 0, stream>>>(PRD, ACC, cs*DI0*DST);
      scan3p<DM0, DI0, LT0, CL0, NC0, L0><<<cs*NC0/4, 256, 0, stream>>>(
          XS, DT, Bb, Cb, GT, m1_alog, m1_D, ACC, m1_ow, Y0, s0);
    }
  }

  // ---- branches 1+2 (m2 shared weights), NC=80 (proven 5 blk/CU config) ----
  {
    const size_t perState = (size_t)NC12*DI2*DST;
    const size_t per = (size_t)LT12*(3*DI2 + 2*DST) + 2*perState;
    int cap = (int)(scrf / per); if (cap < 1) cap = 1; if (cap > NS12) cap = NS12;
    float* XS  = SCR;
    float* DT  = XS + (size_t)cap*LT12*DI2;
    float* Bb  = DT + (size_t)cap*LT12*DI2;
    float* Cb  = Bb + (size_t)cap*LT12*DST;
    float* GT  = Cb + (size_t)cap*LT12*DST;
    float* PRD = GT + (size_t)cap*LT12*DI2;
    float* ACC = PRD + (size_t)cap*perState;
    for (int s0 = 0; s0 < NS12; s0 += cap) {
      int cs = (NS12 - s0 < cap) ? (NS12 - s0) : cap;
      front<DM2, DI2, LT12, CL12, NC12, 1><<<cs*NC12, 256, 0, stream>>>(
          x, gt2, norm2_w, norm2_b, m2_inw, m2_cw, m2_cb, m2_xpw, m2_dtw, m2_dtb,
          m2_alog, XS, DT, Bb, Cb, GT, PRD, ACC, s0);
      scan2<DI2, NC12><<<(cs*DI2*DST + 255)/256, 256, 0, stream>>>(PRD, ACC, cs*DI2*DST);
      scan3p<DM2, DI2, LT12, CL12, NC12, L12><<<cs*NC12/4, 256, 0, stream>>>(
          XS, DT, Bb, Cb, GT, m2_alog, m2_D, ACC, m2_ow, Y12, s0);
    }
  }

  // ---- repack Y0 into fold-friendly layout (SCR is free now) ----
  float* Y0R = SCR;   // aliases the now-dead scratch region
  repack_y0<<<64*48, 128, 0, stream>>>(Y0, Y0R);

  // ---- final fold (fully coalesced) ----
  fold_out2<<<64*128, 192, 0, stream>>>(Y0R, Y12, out);
}

// Round 12
// 767.821 us; speedup vs baseline: 1.0198x; 1.0198x over previous
//
#include <hip/hip_runtime.h>
#include <math.h>

// Problem dims
#define H_   192
#define W_   192
#define C_   128
#define CS_  24

// branch 0 (m1)
#define DM0  32
#define DI0  64
#define L0   2304
#define LT0  2305
#define NS0  64

// branches 1+2 (m2, shared weights) run as 128 sequences
#define DM2  24
#define DI2  48
#define L12  3072
#define LT12 3073
#define NS12 128

#define DST  16
// per-branch chunk counts (NC is a template param; CL = ceil(LT/NC)).
// MEASURED NC series: front12: NC=64 -> 197us, NC=80 (LDS 28,672B, 5 blk/CU)
// -> 179.5us (round 9, +9%). front0: NC=64 -> best total 768.6; NC=104 ->
// 779.5; NC=112 (even at the proven 28,672B) -> 783.1. front0's wint staging
// (16KB/block, 2x front12's) makes extra chunks net-negative — occupancy
// lever pays ONLY where staging amortization stays cheap. Final: 64 / 80.
#define NC0   64
#define CL0   ((LT0 + NC0 - 1) / NC0)     // 37  (NR=40) -> front0 LDS 34,304B, 4 blk/CU
#define NC12  80
#define CL12  ((LT12 + NC12 - 1) / NC12)  // 39  (NR=42) -> front12 LDS 28,672B, 5 blk/CU

__device__ __forceinline__ float sigmoidf_(float x){ return 1.f/(1.f+__expf(-x)); }
__device__ __forceinline__ float siluf_(float x){ return x*sigmoidf_(x); }
__device__ __forceinline__ float softplusf_(float x){ return (x > 20.f) ? x : log1pf(__expf(x)); }
__device__ __forceinline__ float exp2_(float x){
#if __has_builtin(__builtin_amdgcn_exp2f)
  return __builtin_amdgcn_exp2f(x);
#else
  return exp2f(x);
#endif
}
#define LOG2E_ 1.44269504088896f

#define LD4(p)  (*(const float4*)(p))
#define ST4(p,v) (*(float4*)(p) = (v))

// ======== front: gather+LN+in_proj+conv+silu+x_proj+dt+scan1-compose ========
// Round-6 phase structure (measured local optimum). Lessons banked:
// R2: no launch_bounds min-occupancy arg (allocator spills 2.4GB/dispatch);
//     pressure via `#pragma unroll 2`.
// R4: deeper register micro-tiling null (latency already hidden at 4 blk/CU).
// R7: LDS diet to exactly 32,768 gives NO 5th block (160KiB exact, no slack).
// R8: phase-1 gather staging pure overhead — do not stage.
// R9/R10/R11: 28,672B LDS -> 5 blk/CU works; pays on front12 only.
// Phase 2a bound (nt+4)/2: == (nt+3)/2 for odd nt (bit-identical here; all
// nt odd at NC0=64/NC12=80), even-nt-safe if NC changes again.
template<int DM, int DI, int LT, int CL, int NC, int BID>
__global__ __launch_bounds__(256) void front(
    const float* __restrict__ x, const float* __restrict__ gt,
    const float* __restrict__ nw, const float* __restrict__ nb,
    const float* __restrict__ win, const float* __restrict__ cw,
    const float* __restrict__ cb, const float* __restrict__ xpw,
    const float* __restrict__ dtw, const float* __restrict__ dtb,
    const float* __restrict__ Alog,
    float* __restrict__ XS, float* __restrict__ DT,
    float* __restrict__ Bb, float* __restrict__ Cb, float* __restrict__ GATE,
    float* __restrict__ PRD, float* __restrict__ ACC, int seq0)
{
  constexpr int NR  = CL + 3;                  // 40 / 42
  constexpr int R3A = DM*2*DI;                 // wint [k][col]
  constexpr int R3B = CL*36 + DI*36;           // dbl [CL][36] + xpwt [DI][36] (padded)
  constexpr int R3  = (R3A > R3B) ? R3A : R3B;
  __shared__ __align__(16) float smem[2*NR*DI + R3];
  float* xsin = smem;                          // [NR][DI]; phase5+: dtl overlay
  float* dtl  = smem;
  float* xsc  = smem + NR*DI;                  // [NR][DI]; phase1-2: xn [NR][DM]
  float* xn   = xsc;
  float* r3   = smem + 2*NR*DI;
  float* wint = r3;                            // [DM][2*DI] (k-major)
  float* dbl  = r3;                            // [CL][36]: B 0..15, C 16..31, dt 32,33
  float* xpwt = r3 + CL*36;                    // [DI][36]  (k-major, cols 34,35 pad=0)

  const int tid = threadIdx.x;
  const int sc = blockIdx.x / NC, c = blockIdx.x % NC;
  const int gid = seq0 + sc;
  const int t0 = c*CL;
  int nt = LT - t0; if (nt > CL) nt = CL;      // may be <= 0 for tail chunks

  // stage wint[k][col] = win[col*DM + k]
  for (int i = tid; i < DM*2*DI; i += 256) {
    int k = i / (2*DI), col = i - k*(2*DI);
    wint[i] = win[col*DM + k];
  }
  // phase 1: gather + LN -> xn (all NR rows; zero outside sequence)
  {
    int hw = tid >> 5, dm = tid & 31;
    for (int r = hw; r < NR; r += 8) {
      int t = t0 - 3 + r;
      bool inr = (t >= 0 && t < LT);
      float v = 0.f;
      if (inr && dm < DM) {
        if (t == 0) v = gt[dm];
        else {
          int s = t - 1;
          if (BID == 0) {
            int p = s / 48, q = s - p*48;
            int cc = dm*4 + (p&1)*2 + (q&1);
            int ii = p >> 1, jj = q >> 1;
            v = x[cc*(H_*W_) + ((gid>>3)*CS_ + ii)*W_ + (gid&7)*CS_ + jj];
          } else {
            int cc = s / 24, rr = s - cc*24;
            int n = gid & 63, br = gid >> 6;
            int ii = br ? rr : dm;
            int jj = br ? dm : rr;
            v = x[cc*(H_*W_) + ((n>>3)*CS_ + ii)*W_ + (n&7)*CS_ + jj];
          }
        }
      }
      float s1 = (dm < DM) ? v : 0.f;
      float s2 = s1*s1;
      #pragma unroll
      for (int off = 1; off < 32; off <<= 1) {
        s1 += __shfl_xor(s1, off);
        s2 += __shfl_xor(s2, off);
      }
      if (dm < DM) {
        float mean = s1 * (1.f/DM);
        float var = s2 * (1.f/DM) - mean*mean;
        float xv = (v - mean)*rsqrtf(var + 1e-5f)*nw[dm] + nb[dm];
        xn[r*DM + dm] = inr ? xv : 0.f;
      }
    }
  }
  __syncthreads();
  // phase 2a: in_proj xs -> xsin   (2-row x 4-col register tiles)
  for (int idx = tid; idx < ((nt+4)/2)*(DI/4); idx += 256) {
    int rp = idx / (DI/4), dq = idx - rp*(DI/4);
    int r0 = rp*2, r1 = r0 + 1;
    float ax0=0.f, ay0=0.f, az0=0.f, aw0=0.f;
    float ax1=0.f, ay1=0.f, az1=0.f, aw1=0.f;
    #pragma unroll 2
    for (int kq = 0; kq < DM/4; kq++) {
      float4 xa = LD4(xn + r0*DM + kq*4);
      float4 xb = LD4(xn + r1*DM + kq*4);
      const float* wb = wint + (kq*4)*(2*DI) + dq*4;
      float4 w0 = LD4(wb);
      float4 w1 = LD4(wb + 2*DI);
      float4 w2 = LD4(wb + 4*DI);
      float4 w3 = LD4(wb + 6*DI);
      ax0 += xa.x*w0.x + xa.y*w1.x + xa.z*w2.x + xa.w*w3.x;
      ay0 += xa.x*w0.y + xa.y*w1.y + xa.z*w2.y + xa.w*w3.y;
      az0 += xa.x*w0.z + xa.y*w1.z + xa.z*w2.z + xa.w*w3.z;
      aw0 += xa.x*w0.w + xa.y*w1.w + xa.z*w2.w + xa.w*w3.w;
      ax1 += xb.x*w0.x + xb.y*w1.x + xb.z*w2.x + xb.w*w3.x;
      ay1 += xb.x*w0.y + xb.y*w1.y + xb.z*w2.y + xb.w*w3.y;
      az1 += xb.x*w0.z + xb.y*w1.z + xb.z*w2.z + xb.w*w3.z;
      aw1 += xb.x*w0.w + xb.y*w1.w + xb.z*w2.w + xb.w*w3.w;
    }
    ST4(xsin + r0*DI + dq*4, make_float4(ax0,ay0,az0,aw0));
    ST4(xsin + r1*DI + dq*4, make_float4(ax1,ay1,az1,aw1));
  }
  // phase 2b: in_proj z -> GATE = silu(z)   (2-token x 4-col tiles, tail guard)
  for (int idx = tid; idx < ((nt+1)/2)*(DI/4); idx += 256) {
    int tp = idx / (DI/4), dq = idx - tp*(DI/4);
    int lt0 = tp*2, lt1 = lt0 + 1;
    int r0 = lt0 + 3, r1 = lt1 + 3;       // rows exist (<= NR-1), zero-filled
    float ax0=0.f, ay0=0.f, az0=0.f, aw0=0.f;
    float ax1=0.f, ay1=0.f, az1=0.f, aw1=0.f;
    #pragma unroll 2
    for (int kq = 0; kq < DM/4; kq++) {
      float4 xa = LD4(xn + r0*DM + kq*4);
      float4 xb = LD4(xn + r1*DM + kq*4);
      const float* wb = wint + (kq*4)*(2*DI) + DI + dq*4;
      float4 w0 = LD4(wb);
      float4 w1 = LD4(wb + 2*DI);
      float4 w2 = LD4(wb + 4*DI);
      float4 w3 = LD4(wb + 6*DI);
      ax0 += xa.x*w0.x + xa.y*w1.x + xa.z*w2.x + xa.w*w3.x;
      ay0 += xa.x*w0.y + xa.y*w1.y + xa.z*w2.y + xa.w*w3.y;
      az0 += xa.x*w0.z + xa.y*w1.z + xa.z*w2.z + xa.w*w3.z;
      aw0 += xa.x*w0.w + xa.y*w1.w + xa.z*w2.w + xa.w*w3.w;
      ax1 += xb.x*w0.x + xb.y*w1.x + xb.z*w2.x + xb.w*w3.x;
      ay1 += xb.x*w0.y + xb.y*w1.y + xb.z*w2.y + xb.w*w3.y;
      az1 += xb.x*w0.z + xb.y*w1.z + xb.z*w2.z + xb.w*w3.z;
      aw1 += xb.x*w0.w + xb.y*w1.w + xb.z*w2.w + xb.w*w3.w;
    }
    size_t gb = (size_t)sc*LT + t0;
    ST4(GATE + (gb + lt0)*DI + dq*4,
        make_float4(siluf_(ax0), siluf_(ay0), siluf_(az0), siluf_(aw0)));
    if (lt1 < nt)
      ST4(GATE + (gb + lt1)*DI + dq*4,
          make_float4(siluf_(ax1), siluf_(ay1), siluf_(az1), siluf_(aw1)));
  }
  __syncthreads();
  // phase 3: conv+silu -> xsc (+XS), zero-fill rows >= nt; stage xpwt (padded 36)
  for (int idx = tid; idx < NR*(DI/4); idx += 256) {
    int lt = idx / (DI/4), dq = idx - lt*(DI/4);
    int d0 = dq*4;
    float4 o = make_float4(0.f,0.f,0.f,0.f);
    if (lt < nt) {
      float4 a0 = LD4(xsin + (lt+0)*DI + d0);
      float4 a1 = LD4(xsin + (lt+1)*DI + d0);
      float4 a2 = LD4(xsin + (lt+2)*DI + d0);
      float4 a3 = LD4(xsin + (lt+3)*DI + d0);
      float4 w0 = LD4(cw + (d0+0)*4);
      float4 w1 = LD4(cw + (d0+1)*4);
      float4 w2 = LD4(cw + (d0+2)*4);
      float4 w3 = LD4(cw + (d0+3)*4);
      float4 cbq = LD4(cb + d0);
      o.x = siluf_(cbq.x + w0.x*a0.x + w0.y*a1.x + w0.z*a2.x + w0.w*a3.x);
      o.y = siluf_(cbq.y + w1.x*a0.y + w1.y*a1.y + w1.z*a2.y + w1.w*a3.y);
      o.z = siluf_(cbq.z + w2.x*a0.z + w2.y*a1.z + w2.z*a2.z + w2.w*a3.z);
      o.w = siluf_(cbq.w + w3.x*a0.w + w3.y*a1.w + w3.z*a2.w + w3.w*a3.w);
      ST4(XS + ((size_t)sc*LT + t0 + lt)*DI + d0, o);
    }
    ST4(xsc + lt*DI + d0, o);
  }
  for (int i = tid; i < DI*36; i += 256) {
    int k = i / 36, o = i - k*36;
    xpwt[i] = (o < 34) ? xpw[o*DI + k] : 0.f;
  }
  __syncthreads();
  // phase 4: x_proj (2-token x 4-out tiles) -> dbl (B 0..15, C 16..31, dt 32,33)
  for (int idx = tid; idx < ((nt+1)/2)*9; idx += 256) {
    int tp = idx / 9, oq = idx - tp*9;
    int lt0 = tp*2, lt1 = lt0 + 1;       // lt1 <= nt < NR: row exists (zeros)
    float ax0=0.f, ay0=0.f, az0=0.f, aw0=0.f;
    float ax1=0.f, ay1=0.f, az1=0.f, aw1=0.f;
    #pragma unroll 2
    for (int dq = 0; dq < DI/4; dq++) {
      float4 xa = LD4(xsc + lt0*DI + dq*4);
      float4 xb = LD4(xsc + lt1*DI + dq*4);
      const float* wb = xpwt + (dq*4)*36 + oq*4;
      float4 w0 = LD4(wb);
      float4 w1 = LD4(wb + 36);
      float4 w2 = LD4(wb + 72);
      float4 w3 = LD4(wb + 108);
      ax0 += xa.x*w0.x + xa.y*w1.x + xa.z*w2.x + xa.w*w3.x;
      ay0 += xa.x*w0.y + xa.y*w1.y + xa.z*w2.y + xa.w*w3.y;
      az0 += xa.x*w0.z + xa.y*w1.z + xa.z*w2.z + xa.w*w3.z;
      aw0 += xa.x*w0.w + xa.y*w1.w + xa.z*w2.w + xa.w*w3.w;
      ax1 += xb.x*w0.x + xb.y*w1.x + xb.z*w2.x + xb.w*w3.x;
      ay1 += xb.x*w0.y + xb.y*w1.y + xb.z*w2.y + xb.w*w3.y;
      az1 += xb.x*w0.z + xb.y*w1.z + xb.z*w2.z + xb.w*w3.z;
      aw1 += xb.x*w0.w + xb.y*w1.w + xb.z*w2.w + xb.w*w3.w;
    }
    float av0[4] = {ax0, ay0, az0, aw0};
    float av1[4] = {ax1, ay1, az1, aw1};
    int o0 = oq*4;
    #pragma unroll
    for (int j = 0; j < 4; j++) {
      int o = o0 + j;
      if (o < 2)       dbl[lt0*36 + 32 + o] = av0[j];
      else if (o < 34) dbl[lt0*36 + (o-2)] = av0[j];
    }
    if (lt1 < nt) {
      #pragma unroll
      for (int j = 0; j < 4; j++) {
        int o = o0 + j;
        if (o < 2)       dbl[lt1*36 + 32 + o] = av1[j];
        else if (o < 34) dbl[lt1*36 + (o-2)] = av1[j];
      }
    }
  }
  __syncthreads();
  // phase 4b: vectorized B/C global writes from dbl
  for (int idx = tid; idx < nt*8; idx += 256) {
    int lt = idx >> 3, q = idx & 7;
    float4 v = LD4(dbl + lt*36 + q*4);
    size_t tb = (size_t)sc*LT + t0 + lt;
    if (q < 4) ST4(Bb + tb*DST + q*4, v);
    else       ST4(Cb + tb*DST + (q-4)*4, v);
  }
  // phase 5: dt -> dtl (overlays xsin) + DT
  for (int idx = tid; idx < nt*(DI/4); idx += 256) {
    int lt = idx / (DI/4), dq = idx - lt*(DI/4);
    int d0 = dq*4;
    float t0v = dbl[lt*36 + 32], t1v = dbl[lt*36 + 33];
    float4 w0 = LD4(dtw + 2*d0);
    float4 w1 = LD4(dtw + 2*d0 + 4);
    float4 b4 = LD4(dtb + d0);
    float4 r;
    r.x = softplusf_(t0v*w0.x + t1v*w0.y + b4.x);
    r.y = softplusf_(t0v*w0.z + t1v*w0.w + b4.y);
    r.z = softplusf_(t0v*w1.x + t1v*w1.y + b4.z);
    r.w = softplusf_(t0v*w1.z + t1v*w1.w + b4.w);
    ST4(dtl + lt*DI + d0, r);
    ST4(DT + ((size_t)sc*LT + t0 + lt)*DI + d0, r);
  }
  __syncthreads();
  // phase 6: chunk composition, thread = (d, state-quad); empty chunks emit P=1,S=0
  for (int p = tid; p < DI*4; p += 256) {
    int d = p >> 2, iq = p & 3;
    float4 al = LD4(Alog + d*DST + iq*4);
    float A0 = -__expf(al.x)*LOG2E_, A1 = -__expf(al.y)*LOG2E_;
    float A2 = -__expf(al.z)*LOG2E_, A3 = -__expf(al.w)*LOG2E_;
    float P0=1.f,P1=1.f,P2=1.f,P3=1.f, S0=0.f,S1=0.f,S2=0.f,S3=0.f;
    for (int lt = 0; lt < nt; lt++) {
      float dtv = dtl[lt*DI + d];
      float du = dtv * xsc[lt*DI + d];
      float4 Bq = LD4(dbl + lt*36 + iq*4);
      float a0 = exp2_(dtv*A0), a1 = exp2_(dtv*A1);
      float a2 = exp2_(dtv*A2), a3 = exp2_(dtv*A3);
      P0 *= a0; S0 = S0*a0 + du*Bq.x;
      P1 *= a1; S1 = S1*a1 + du*Bq.y;
      P2 *= a2; S2 = S2*a2 + du*Bq.z;
      P3 *= a3; S3 = S3*a3 + du*Bq.w;
    }
    size_t ob = (size_t)(sc*NC + c)*DI*DST + d*DST + iq*4;
    ST4(PRD + ob, make_float4(P0,P1,P2,P3));
    ST4(ACC + ob, make_float4(S0,S1,S2,S3));
  }
}

// ======== scan2: chunk-level scan; leaves per-chunk h_init in ACC ========
template<int DI, int NC>
__global__ __launch_bounds__(256) void scan2(const float* __restrict__ PRD, float* __restrict__ ACC, int nthread) {
  int tid = blockIdx.x*256 + threadIdx.x;
  if (tid >= nthread) return;
  int sc = tid / (DI*DST);
  int rem = tid - sc*(DI*DST);
  float h = 0.f;
  size_t idx = (size_t)sc*NC*DI*DST + rem;
  #pragma unroll 4
  for (int c = 0; c < NC; c++) {
    float p = PRD[idx];
    float s = ACC[idx];
    ACC[idx] = h;
    h = p*h + s;
    idx += (size_t)DI*DST;
  }
}

// ======== scan3p v2: 4 chunks per 256-thread block, one wave per chunk ========
template<int DM, int DI, int LT, int CL, int NC, int LSEQ>
__global__ __launch_bounds__(256) void scan3p(
    const float* __restrict__ XS, const float* __restrict__ DT,
    const float* __restrict__ Bb, const float* __restrict__ Cb,
    const float* __restrict__ GATE, const float* __restrict__ Alog,
    const float* __restrict__ Dp, const float* __restrict__ ACC,
    const float* __restrict__ wo, float* __restrict__ Y, int seq0)
{
  constexpr int DIP = DI + 4;   // pad to break stride-DI bank pattern
  __shared__ __align__(16) float wot[DM*DIP];
  __shared__ __align__(16) float gl[4][8*DI];
  const int tid = threadIdx.x;
  for (int i = tid; i < DM*DI; i += 256) {
    int dm = i / DI, k = i - dm*DI;
    wot[dm*DIP + k] = wo[i];
  }
  const int lane = tid & 63;
  const int w = tid >> 6;
  const int g = __builtin_amdgcn_readfirstlane(blockIdx.x*4 + w);
  const int sc = g / NC, c = g - (g/NC)*NC;
  float* glw = &gl[w][0];
  int d = lane;
  float A[DST], h[DST];
  float Dd = 0.f;
  if (d < DI) {
    const float4* Ap = (const float4*)(Alog + d*DST);
    #pragma unroll
    for (int q = 0; q < 4; q++) {
      float4 av = Ap[q];
      A[q*4+0] = -__expf(av.x)*LOG2E_; A[q*4+1] = -__expf(av.y)*LOG2E_;
      A[q*4+2] = -__expf(av.z)*LOG2E_; A[q*4+3] = -__expf(av.w)*LOG2E_;
    }
    const float4* hp = (const float4*)(ACC + ((size_t)g*DI + d)*DST);
    #pragma unroll
    for (int q = 0; q < 4; q++) ((float4*)h)[q] = hp[q];
    Dd = Dp[d];
  }
  int t0 = c*CL, t1 = t0 + CL; if (t1 > LT) t1 = LT;
  size_t base = (size_t)sc*LT;
  size_t ybase = (size_t)(seq0 + sc)*LSEQ;
  int bt = 0, tstart = t0;
  __syncthreads();            // wot ready (only block-wide barrier)
  for (int t = t0; t < t1; t++) {
    if (d < DI) {
      size_t tb = base + t;
      float dtv = DT[tb*DI + d];
      float xsv = XS[tb*DI + d];
      float gv  = GATE[tb*DI + d];
      float du = dtv*xsv;
      float Bv[DST], Cv[DST];
      const float4* Bp = (const float4*)(Bb + tb*DST);
      const float4* Cp = (const float4*)(Cb + tb*DST);
      ((float4*)Bv)[0]=Bp[0]; ((float4*)Bv)[1]=Bp[1]; ((float4*)Bv)[2]=Bp[2]; ((float4*)Bv)[3]=Bp[3];
      ((float4*)Cv)[0]=Cp[0]; ((float4*)Cv)[1]=Cp[1]; ((float4*)Cv)[2]=Cp[2]; ((float4*)Cv)[3]=Cp[3];
      float y = 0.f;
      #pragma unroll
      for (int i = 0; i < DST; i++) {
        float a = exp2_(dtv*A[i]);
        h[i] = h[i]*a + du*Bv[i];
        y += h[i]*Cv[i];
      }
      glw[bt*DI + d] = (y + xsv*Dd) * gv;
    }
    bt++;
    if (bt == 8 || t == t1 - 1) {
      // wave-local fence: gl writes retired before cross-lane reads
      asm volatile("s_waitcnt lgkmcnt(0)" ::: "memory");
      __builtin_amdgcn_wave_barrier();
      for (int o = lane; o < bt*DM; o += 64) {
        int b = o / DM, dm = o - b*DM;
        int tt = tstart + b;
        if (tt > 0) {
          float acc = 0.f;
          const float* gr = glw + b*DI;
          const float* wr = wot + dm*DIP;
          #pragma unroll
          for (int kq = 0; kq < DI/4; kq++) {
            float4 g4 = LD4(gr + kq*4);
            float4 w4 = LD4(wr + kq*4);
            acc += g4.x*w4.x + g4.y*w4.y + g4.z*w4.z + g4.w*w4.w;
          }
          Y[(ybase + tt - 1)*DM + dm] = acc;
        }
      }
      // reads retired before next batch overwrites gl
      asm volatile("s_waitcnt lgkmcnt(0)" ::: "memory");
      __builtin_amdgcn_wave_barrier();
      bt = 0; tstart = t + 1;
    }
  }
}

// ======== repack_y0: Y0[n][token(p,q)][dm] -> Y0R[n][c][i][j] ========
__global__ __launch_bounds__(128) void repack_y0(const float* __restrict__ Y0,
                                                 float* __restrict__ Y0R) {
  __shared__ float l[48*33];
  int n = blockIdx.x / 48, p = blockIdx.x - (blockIdx.x/48)*48;
  int tid = threadIdx.x;
  const float* src = Y0 + ((size_t)n*L0 + p*48)*DM0;
  for (int i = tid; i < 48*32; i += 128) {
    int q = i >> 5, dm = i & 31;
    l[q*33 + dm] = src[i];
  }
  __syncthreads();
  int p2 = p >> 1, ppar = p & 1;
  for (int o = tid; o < 1536; o += 128) {
    int dm = o / 48, rem = o - dm*48;
    int qpar = rem / 24, j = rem - qpar*24;
    int c = 4*dm + 2*ppar + qpar;
    Y0R[((size_t)(n*128 + c)*24 + p2)*24 + j] = l[(2*j + qpar)*33 + dm];
  }
}

// ======== fold_out2: all three gathers 576-float contiguous blocks ========
__global__ __launch_bounds__(192) void fold_out2(const float* __restrict__ Y0R,
                                                 const float* __restrict__ Y12,
                                                 float* __restrict__ out) {
  __shared__ float m0l[576];
  __shared__ float o1l[24*25];
  __shared__ float o2l[576];
  int n = blockIdx.x >> 7, c = blockIdx.x & 127;
  int tid = threadIdx.x;
  const float* m0p = Y0R + (size_t)(n*128 + c)*576;
  const float* o1p = Y12 + ((size_t)n*L12 + c*24)*DM2;        // [j][i]
  const float* o2p = Y12 + ((size_t)(64+n)*L12 + c*24)*DM2;   // [i][j]
  for (int i = tid; i < 576; i += 192) {
    m0l[i] = m0p[i];
    int r = i / 24, col = i - r*24;
    o1l[r*25 + col] = o1p[i];
    o2l[i] = o2p[i];
  }
  __syncthreads();
  for (int e = tid; e < 576; e += 192) {
    int hh = e / 192, w = e - hh*192;
    int i = hh*8 + w/24, j = w - (w/24)*24;
    float v = (m0l[i*24 + j] + o1l[j*25 + i] + o2l[i*24 + j]) * (1.f/3.f);
    out[(size_t)c*(H_*W_) + (size_t)(n*3 + hh)*W_ + w] = v;
  }
}

extern "C" void kernel_launch(void* const* d_in, const int* in_sizes, int n_in,
                              void* d_out, int out_size, void* d_ws, size_t ws_size,
                              hipStream_t stream) {
  const float* x       = (const float*)d_in[0];
  const float* norm_w  = (const float*)d_in[1];
  const float* norm_b  = (const float*)d_in[2];
  const float* norm2_w = (const float*)d_in[3];
  const float* norm2_b = (const float*)d_in[4];
  const float* gt1     = (const float*)d_in[5];
  const float* gt2     = (const float*)d_in[6];
  const float* m1_inw  = (const float*)d_in[7];
  const float* m1_cw   = (const float*)d_in[8];
  const float* m1_cb   = (const float*)d_in[9];
  const float* m1_xpw  = (const float*)d_in[10];
  const float* m1_dtw  = (const float*)d_in[11];
  const float* m1_dtb  = (const float*)d_in[12];
  const float* m1_alog = (const float*)d_in[13];
  const float* m1_D    = (const float*)d_in[14];
  const float* m1_ow   = (const float*)d_in[15];
  const float* m2_inw  = (const float*)d_in[16];
  const float* m2_cw   = (const float*)d_in[17];
  const float* m2_cb   = (const float*)d_in[18];
  const float* m2_xpw  = (const float*)d_in[19];
  const float* m2_dtw  = (const float*)d_in[20];
  const float* m2_dtb  = (const float*)d_in[21];
  const float* m2_alog = (const float*)d_in[22];
  const float* m2_D    = (const float*)d_in[23];
  const float* m2_ow   = (const float*)d_in[24];
  float* out = (float*)d_out;

  size_t wsf = ws_size / sizeof(float);

  // persistent projection buffers
  const size_t nY0  = (size_t)NS0*L0*DM0;    // 4,718,592
  const size_t nY12 = (size_t)NS12*L12*DM2;  // 9,437,184
  float* Y0  = (float*)d_ws;
  float* Y12 = Y0 + nY0;
  float* SCR = Y12 + nY12;
  size_t scrf = wsf - (nY0 + nY12);

  // ---- branch 0 (m1), NC=64 (measured best: chunk overhead beats 5th block) ----
  {
    const size_t perState = (size_t)NC0*DI0*DST;
    const size_t per = (size_t)LT0*(3*DI0 + 2*DST) + 2*perState;
    int cap = (int)(scrf / per); if (cap < 1) cap = 1; if (cap > NS0) cap = NS0;
    float* XS  = SCR;
    float* DT  = XS + (size_t)cap*LT0*DI0;
    float* Bb  = DT + (size_t)cap*LT0*DI0;
    float* Cb  = Bb + (size_t)cap*LT0*DST;
    float* GT  = Cb + (size_t)cap*LT0*DST;
    float* PRD = GT + (size_t)cap*LT0*DI0;
    float* ACC = PRD + (size_t)cap*perState;
    for (int s0 = 0; s0 < NS0; s0 += cap) {
      int cs = (NS0 - s0 < cap) ? (NS0 - s0) : cap;
      front<DM0, DI0, LT0, CL0, NC0, 0><<<cs*NC0, 256, 0, stream>>>(
          x, gt1, norm_w, norm_b, m1_inw, m1_cw, m1_cb, m1_xpw, m1_dtw, m1_dtb,
          m1_alog, XS, DT, Bb, Cb, GT, PRD, ACC, s0);
      scan2<DI0, NC0><<<(cs*DI0*DST + 255)/256, 256, 0, stream>>>(PRD, ACC, cs*DI0*DST);
      scan3p<DM0, DI0, LT0, CL0, NC0, L0><<<cs*NC0/4, 256, 0, stream>>>(
          XS, DT, Bb, Cb, GT, m1_alog, m1_D, ACC, m1_ow, Y0, s0);
    }
  }

  // ---- branches 1+2 (m2 shared weights), NC=80 (proven 5 blk/CU config) ----
  {
    const size_t perState = (size_t)NC12*DI2*DST;
    const size_t per = (size_t)LT12*(3*DI2 + 2*DST) + 2*perState;
    int cap = (int)(scrf / per); if (cap < 1) cap = 1; if (cap > NS12) cap = NS12;
    float* XS  = SCR;
    float* DT  = XS + (size_t)cap*LT12*DI2;
    float* Bb  = DT + (size_t)cap*LT12*DI2;
    float* Cb  = Bb + (size_t)cap*LT12*DST;
    float* GT  = Cb + (size_t)cap*LT12*DST;
    float* PRD = GT + (size_t)cap*LT12*DI2;
    float* ACC = PRD + (size_t)cap*perState;
    for (int s0 = 0; s0 < NS12; s0 += cap) {
      int cs = (NS12 - s0 < cap) ? (NS12 - s0) : cap;
      front<DM2, DI2, LT12, CL12, NC12, 1><<<cs*NC12, 256, 0, stream>>>(
          x, gt2, norm2_w, norm2_b, m2_inw, m2_cw, m2_cb, m2_xpw, m2_dtw, m2_dtb,
          m2_alog, XS, DT, Bb, Cb, GT, PRD, ACC, s0);
      scan2<DI2, NC12><<<(cs*DI2*DST + 255)/256, 256, 0, stream>>>(PRD, ACC, cs*DI2*DST);
      scan3p<DM2, DI2, LT12, CL12, NC12, L12><<<cs*NC12/4, 256, 0, stream>>>(
          XS, DT, Bb, Cb, GT, m2_alog, m2_D, ACC, m2_ow, Y12, s0);
    }
  }

  // ---- repack Y0 into fold-friendly layout (SCR is free now) ----
  float* Y0R = SCR;   // aliases the now-dead scratch region
  repack_y0<<<64*48, 128, 0, stream>>>(Y0, Y0R);

  // ---- final fold (fully coalesced) ----
  fold_out2<<<64*128, 192, 0, stream>>>(Y0R, Y12, out);
}